// Round 3
// baseline (359.535 us; speedup 1.0000x reference)
//
#include <hip/hip_runtime.h>
#include <math.h>

// Problem: B=16, LQ=1024, LK=1024, DK=256, DV=256, fp32 in/out, mask int32.
// Identity: softmax_k(q_s + k_s, mask) == mask-weighted softmax of k_s alone
// (q_s constant over k cancels; masked entries exactly -1e9 -> weight 0).
// query is never read. k_s ~ N(0,16^2) so softmax mass concentrates in the
// top few keys: keep candidates e >= 1e-11 * e_max (C ~ 50-90 per batch),
// track exact excluded mass excl; per row verify excl <= 1e-4 * Z else take
// an exact dense fallback (expected ~0-2 rows total).

#define NB     16
#define NL     1024
#define ND     256
#define CMAX   256      // candidate list capacity (overflow -> counted in excl)
#define NSTAGE 56       // candidate V rows staged in LDS (56 KB)
#define THRESH 1e-11f
#define RELCHK 1e-4f

// ---------------- Kernel A: ks[b,k] = dot(key[b,k,:], w) -----------------
__global__ __launch_bounds__(256)
void ks_kernel(const float* __restrict__ key, const float* __restrict__ w,
               float* __restrict__ ks) {
    int wid  = threadIdx.x >> 6;
    int lane = threadIdx.x & 63;
    int row  = blockIdx.x * 4 + wid;               // 0 .. NB*NL-1
    const float4* krow = (const float4*)(key + (size_t)row * ND);
    float4 kv = krow[lane];
    float4 wv = ((const float4*)w)[lane];
    float p = kv.x * wv.x + kv.y * wv.y + kv.z * wv.z + kv.w * wv.w;
    #pragma unroll
    for (int off = 32; off > 0; off >>= 1)
        p += __shfl_xor(p, off, 64);
    if (lane == 0) ks[row] = p;
}

// ---- Kernel B: per batch: max, e=exp(ks-m), threshold compaction --------
// No sort. excl = exact sum of all e NOT in the candidate list.
__global__ __launch_bounds__(1024)
void compact_kernel(const float* __restrict__ ks, float* __restrict__ e_full,
                    int* __restrict__ cand_k, float* __restrict__ cand_e,
                    int* __restrict__ Carr, float* __restrict__ exclArr) {
    __shared__ float red[NL];
    __shared__ int cnt;
    const int b = blockIdx.x;
    const int t = threadIdx.x;

    float v = ks[b * NL + t];
    red[t] = v;
    __syncthreads();
    for (int off = 512; off > 0; off >>= 1) {
        if (t < off) red[t] = fmaxf(red[t], red[t + off]);
        __syncthreads();
    }
    float m = red[0];
    if (t == 0) cnt = 0;
    __syncthreads();

    float e = __expf(v - m);            // e in (0,1]
    e_full[b * NL + t] = e;
    bool kept = false;
    if (e >= THRESH) {
        int pos = atomicAdd(&cnt, 1);   // order irrelevant: any-order summation
        if (pos < CMAX) {
            cand_k[b * CMAX + pos] = t;
            cand_e[b * CMAX + pos] = e;
            kept = true;
        }
    }
    red[t] = kept ? 0.0f : e;           // excluded mass (incl. overflow)
    __syncthreads();
    for (int off = 512; off > 0; off >>= 1) {
        if (t < off) red[t] += red[t + off];
        __syncthreads();
    }
    if (t == 0) { Carr[b] = min(cnt, CMAX); exclArr[b] = red[0]; }
}

// ---------------- Kernel C: out[b,q,:] = sum_k p * value[b,k,:] ----------
// 512 blocks x 1024 thr: block = 32 q-rows of one batch; wave = 2 rows.
// Lane j loads mask[row][cand_k[j]] -> ballot -> union bit-walk over both
// rows so each V read (LDS-staged) is shared. Exact dense fallback per row
// when the excluded-mass check fails (~never).
__global__ __launch_bounds__(1024)
void attn_kernel(const float* __restrict__ value, const int* __restrict__ mask,
                 const float* __restrict__ e_full,
                 const int* __restrict__ cand_k, const float* __restrict__ cand_e,
                 const int* __restrict__ Carr, const float* __restrict__ exclArr,
                 float* __restrict__ out) {
    __shared__ float ldsV[NSTAGE * ND];   // 56 KB
    __shared__ float e_l[CMAX];
    __shared__ int   k_l[CMAX];

    const int wid   = threadIdx.x >> 6;
    const int lane  = threadIdx.x & 63;
    const int b     = blockIdx.x >> 5;     // 32 blocks per batch
    const int qtile = blockIdx.x & 31;     // 32 rows per block
    const int C     = Carr[b];
    const float excl = exclArr[b];

    if (threadIdx.x < CMAX) {
        e_l[threadIdx.x] = cand_e[b * CMAX + threadIdx.x];
        k_l[threadIdx.x] = cand_k[b * CMAX + threadIdx.x];
    }
    __syncthreads();

    const float4* vbase = (const float4*)(value + (size_t)b * NL * ND);
    const int nst = min(C, NSTAGE);
    for (int r = wid; r < nst; r += 16)
        ((float4*)ldsV)[r * 64 + lane] = vbase[(size_t)k_l[r] * 64 + lane];
    __syncthreads();

    const int q0   = qtile * 32 + wid * 2;     // two consecutive q-rows
    const int row0 = b * NL + q0;
    const int* mrow0 = mask + (size_t)row0 * NL;
    const int* mrow1 = mrow0 + NL;

    float4 acc0 = make_float4(0.f, 0.f, 0.f, 0.f);
    float4 acc1 = make_float4(0.f, 0.f, 0.f, 0.f);
    float Z0 = 0.0f, Z1 = 0.0f;

    const int nchunk = (C + 63) >> 6;
    for (int c = 0; c < nchunk; ++c) {
        const int jj = c * 64 + lane;
        int kj = (jj < C) ? k_l[jj] : 0;
        int m0 = (jj < C) ? mrow0[kj] : 0;
        int m1 = (jj < C) ? mrow1[kj] : 0;
        unsigned long long bits0 = __ballot(m0 != 0);
        unsigned long long bits1 = __ballot(m1 != 0);
        unsigned long long u = bits0 | bits1;
        while (u) {
            const int j = __builtin_ctzll(u);
            u &= u - 1;
            const int idx = c * 64 + j;
            const float e = e_l[idx];
            float4 v;
            if (idx < NSTAGE) v = ((const float4*)ldsV)[idx * 64 + lane];
            else              v = vbase[(size_t)k_l[idx] * 64 + lane];
            const unsigned long long bit = 1ull << j;
            if (bits0 & bit) {
                Z0 += e;
                acc0.x += e * v.x; acc0.y += e * v.y;
                acc0.z += e * v.z; acc0.w += e * v.w;
            }
            if (bits1 & bit) {
                Z1 += e;
                acc1.x += e * v.x; acc1.y += e * v.y;
                acc1.z += e * v.z; acc1.w += e * v.w;
            }
        }
    }

    // epilogue + (rare) exact dense fallback
    #pragma unroll
    for (int r = 0; r < 2; ++r) {
        const float Z   = (r == 0) ? Z0 : Z1;
        const float4 a  = (r == 0) ? acc0 : acc1;
        const int row   = row0 + r;
        const int* mrow = (r == 0) ? mrow0 : mrow1;
        float4* orow = (float4*)(out + (size_t)row * ND);
        if (Z > 0.0f && excl <= RELCHK * Z) {
            const float inv = 1.0f / Z;
            orow[lane] = make_float4(a.x * inv, a.y * inv, a.z * inv, a.w * inv);
        } else {
            // exact: sum ALL unmasked keys
            float Zf = 0.0f;
            float4 af = make_float4(0.f, 0.f, 0.f, 0.f);
            for (int c = 0; c < NL / 64; ++c) {
                int mk = mrow[c * 64 + lane];
                unsigned long long bits = __ballot(mk != 0);
                while (bits) {
                    const int j = __builtin_ctzll(bits);
                    bits &= bits - 1;
                    const int k = c * 64 + j;
                    const float e = e_full[b * NL + k];
                    float4 v = vbase[(size_t)k * 64 + lane];
                    Zf += e;
                    af.x += e * v.x; af.y += e * v.y;
                    af.z += e * v.z; af.w += e * v.w;
                }
            }
            if (Zf > 0.0f) {
                const float inv = 1.0f / Zf;
                orow[lane] = make_float4(af.x * inv, af.y * inv, af.z * inv, af.w * inv);
            } else {
                // all 1024 masked: softmax of constant -1e9 -> uniform average
                float4 s = make_float4(0.f, 0.f, 0.f, 0.f);
                for (int k = 0; k < NL; ++k) {
                    float4 v = vbase[(size_t)k * 64 + lane];
                    s.x += v.x; s.y += v.y; s.z += v.z; s.w += v.w;
                }
                const float inv = 1.0f / (float)NL;
                orow[lane] = make_float4(s.x * inv, s.y * inv, s.z * inv, s.w * inv);
            }
        }
    }
}

extern "C" void kernel_launch(void* const* d_in, const int* in_sizes, int n_in,
                              void* d_out, int out_size, void* d_ws, size_t ws_size,
                              hipStream_t stream) {
    // setup_inputs order: query, key, value, w, mask   (query unused!)
    const float* key   = (const float*)d_in[1];
    const float* value = (const float*)d_in[2];
    const float* w     = (const float*)d_in[3];
    const int*   mask  = (const int*)d_in[4];
    float*       outp  = (float*)d_out;

    float* ks     = (float*)d_ws;                    // 16*1024 f32
    float* e_full = ks + NB * NL;                    // 16*1024 f32
    int*   cand_k = (int*)(e_full + NB * NL);        // 16*256 i32
    float* cand_e = (float*)(cand_k + NB * CMAX);    // 16*256 f32
    int*   Carr   = (int*)(cand_e + NB * CMAX);      // 16 i32
    float* exclA  = (float*)(Carr + NB);             // 16 f32

    ks_kernel     <<<NB * NL / 4, 256, 0, stream>>>(key, w, ks);
    compact_kernel<<<NB, 1024, 0, stream>>>(ks, e_full, cand_k, cand_e, Carr, exclA);
    attn_kernel   <<<NB * NL / 32, 1024, 0, stream>>>(value, mask, e_full,
                                                      cand_k, cand_e, Carr, exclA, outp);
}